// Round 8
// baseline (6022.430 us; speedup 1.0000x reference)
//
#include <hip/hip_runtime.h>
#include <hip/hip_bf16.h>
#include <stdint.h>

// Problem dims (fixed by reference)
#define B_   16
#define T_   512
#define V_   8192
#define E_   512
#define H_   1024
#define BT_  (B_ * T_)   // 8192 rows, row r = b*T + t
#define H4_  (4 * H_)    // 4096

typedef __attribute__((ext_vector_type(8))) short   short8;
typedef __attribute__((ext_vector_type(8))) __bf16  bf16x8;
typedef __attribute__((ext_vector_type(4))) float   f32x4;
typedef __attribute__((ext_vector_type(4))) short   short4v;
typedef unsigned long long ull;

__device__ __forceinline__ float bf2f(short s) {
  union { unsigned u; float f; } x;
  x.u = ((unsigned)(unsigned short)s) << 16;
  return x.f;
}
__device__ __forceinline__ short f2bf(float f) {
  union { float f; unsigned u; } x; x.f = f;
  unsigned u = x.u;
  u = (u + 0x7fffu + ((u >> 16) & 1u)) >> 16;   // RNE
  return (short)u;
}
__device__ __forceinline__ f32x4 mfma16(short8 a, short8 b, f32x4 c) {
  return __builtin_amdgcn_mfma_f32_16x16x32_bf16(
      __builtin_bit_cast(bf16x8, a), __builtin_bit_cast(bf16x8, b), c, 0, 0, 0);
}
__device__ __forceinline__ float sigm(float x) { return 1.f / (1.f + __expf(-x)); }
__device__ __forceinline__ float tanh_f(float x) { return 1.f - 2.f / (__expf(2.f * x) + 1.f); }

__device__ __forceinline__ short8 mk8(ull lo, ull hi) {
  union { ull u[2]; short8 s; } c;
  c.u[0] = lo; c.u[1] = hi;
  return c.s;
}

// ---------------------------------------------------------------------------
// 1) column L2-norm scales
__global__ __launch_bounds__(256) void colscale(const float* __restrict__ W,
                                                const float* __restrict__ g,
                                                float* __restrict__ sc, int Kr, int N) {
  int j = blockIdx.x * 256 + threadIdx.x;
  if (j >= N) return;
  float ss = 0.f;
  for (int i = 0; i < Kr; ++i) { float v = W[(long)i * N + j]; ss = fmaf(v, v, ss); }
  sc[j] = g[j] / fmaxf(sqrtf(ss), 1e-12f);
}

// 2) WT[j][i] = bf16(W[i][j] * sc[j]) — LDS 32x32 tile transpose
__global__ __launch_bounds__(256) void transpose_cast(const float* __restrict__ W,
                                                      const float* __restrict__ sc,
                                                      short* __restrict__ WT, int Kr, int N) {
  __shared__ float tile[32][33];
  int nbi = Kr >> 5;
  int bi = blockIdx.x % nbi, bj = blockIdx.x / nbi;
  int i0 = bi << 5, j0 = bj << 5;
  int tx = threadIdx.x & 31, ty = threadIdx.x >> 5;   // 32 x 8
  for (int yy = ty; yy < 32; yy += 8)
    tile[yy][tx] = W[(long)(i0 + yy) * N + j0 + tx];
  __syncthreads();
  for (int yy = ty; yy < 32; yy += 8) {
    int j = j0 + yy;
    WT[(long)j * Kr + i0 + tx] = f2bf(tile[tx][yy] * sc[j]);
  }
}

// 3) plain f32 -> bf16 cast
__global__ __launch_bounds__(256) void castbf(const float* __restrict__ src,
                                              short* __restrict__ dst, long n) {
  long i = ((long)blockIdx.x * 256 + threadIdx.x) * 4;
  if (i + 3 < n) {
    float4 v = *(const float4*)(src + i);
    short4v o = { f2bf(v.x), f2bf(v.y), f2bf(v.z), f2bf(v.w) };
    *(short4v*)(dst + i) = o;
  }
}

// 4) embedding gather with padding_idx=0 -> zeros
__global__ __launch_bounds__(256) void embed_gather(const int* __restrict__ xs,
                                                    const float* __restrict__ ew,
                                                    short* __restrict__ x) {
  int r = blockIdx.x;
  int idx = xs[r];
  const float* src = ew + (long)idx * E_;
  for (int e = threadIdx.x; e < E_; e += 256) {
    float v = (idx == 0) ? 0.f : src[e];
    x[(long)r * E_ + e] = f2bf(v);
  }
}

// ---------------------------------------------------------------------------
// Generic 128x128-tile bf16 MFMA GEMM: C[M][N](bf16) = A[M][K] @ BT[N][K]^T (+bias)
__global__ __launch_bounds__(256) void gemm_bt(const short* __restrict__ A,
                                               const short* __restrict__ BT,
                                               const float* __restrict__ bias,
                                               short* __restrict__ C,
                                               int M, int N, int K) {
  int ntiles = N >> 7;
  int tM = (blockIdx.x / ntiles) << 7;
  int tN = (blockIdx.x % ntiles) << 7;
  int w = threadIdx.x >> 6, lane = threadIdx.x & 63;
  int mo = tM + ((w & 1) << 6), no = tN + ((w >> 1) << 6);
  int lr = lane & 15, lk8 = (lane >> 4) << 3, q = lane >> 4;
  f32x4 acc[4][4] = {};
  const short* Ap = A + (long)(mo + lr) * K + lk8;
  const short* Bp = BT + (long)(no + lr) * K + lk8;
  for (int k0 = 0; k0 < K; k0 += 32) {
    short8 af[4], bfr[4];
#pragma unroll
    for (int i = 0; i < 4; ++i) af[i] = *(const short8*)(Ap + (long)16 * i * K + k0);
#pragma unroll
    for (int j = 0; j < 4; ++j) bfr[j] = *(const short8*)(Bp + (long)16 * j * K + k0);
#pragma unroll
    for (int i = 0; i < 4; ++i)
#pragma unroll
      for (int j = 0; j < 4; ++j)
        acc[i][j] = mfma16(af[i], bfr[j], acc[i][j]);
  }
  float pbv[4];
#pragma unroll
  for (int j = 0; j < 4; ++j) pbv[j] = bias ? bias[no + 16 * j + lr] : 0.f;
#pragma unroll
  for (int i = 0; i < 4; ++i)
#pragma unroll
    for (int j = 0; j < 4; ++j)
#pragma unroll
      for (int r = 0; r < 4; ++r) {
        int row = mo + 16 * i + 4 * q + r;      // C/D layout: row = quad*4+reg
        int col = no + 16 * j + lr;             //             col = lane&15
        C[(long)row * N + col] = f2bf(acc[i][j][r] + pbv[j]);
      }
}

// ---------------------------------------------------------------------------
// FUSED persistent kernel: 256 WGs.
//   blocks 0..63   : recurrent mLSTM scan (round-2 proven structure).
//   blocks 64..255 : logits workers, STATIC vb-partition with XCD affinity.
//
// Anti-burst design (round-6 lesson: phase release was a thundering herd):
//  * worker wid owns ONE 128-col vb block (64 vb x 3 workers = 192). Workers
//    sharing an XCD (blockIdx round-robin: wid&7) cover one 8-vb slice, so
//    2 MB of pwb stays hot in that XCD's L2 all kernel long.
//  * phase release staggered by (vb&15)*2 scan-steps (off at p=3).
//  * expsum partials: plain stores keyed by (vb, column-half) — ROUND-7 FIX:
//    waves w and w+2 cover different 64-col halves of the same rows, so the
//    partial slot must include (w>>1). 128 slots x BT_ floats, exactly one
//    producer wave each; folded by row_nll. Zero atomics.
// hs visibility: scan publishes hs agent-scope + drain BEFORE prog flag;
// workers first touch an hs line only after the gate (proven r6, absmax 0).
#define NWG_   64
#define NLOG_  192

__device__ __forceinline__ void logits_work_static(
    int tid, int vb, int k3,
    const short* __restrict__ hs, const short* __restrict__ pwb,
    const float* __restrict__ pb, const int* __restrict__ ys,
    float* __restrict__ sumexp_p, float* __restrict__ logit_y,
    unsigned* __restrict__ prog) {
  const int w = tid >> 6, lane = tid & 63;
  const int lr = lane & 15, q = lane >> 4;
  const int lk8 = q << 3;
  const int tN = vb << 7;
  const int no = tN + ((w >> 1) << 6);
  // partial slot: (vb, half) — each wave-half has exactly one producer
  float* sump_slot = sumexp_p + (((long)(vb << 1) | (w >> 1)) << 13);
  float pbv[4];
#pragma unroll
  for (int j = 0; j < 4; ++j) pbv[j] = pb[no + 16 * j + lr];
  for (int p = 0; p < 4; ++p) {
    // staggered release: phase data ready at (p+1)*128; spread the herd
    const unsigned target = (unsigned)(((p + 1) << 7) + ((p < 3) ? ((vb & 15) << 1) : 0));
    while (__hip_atomic_load(prog + tid, __ATOMIC_RELAXED,
                             __HIP_MEMORY_SCOPE_AGENT) < target)
      __builtin_amdgcn_s_sleep(127);     // thin AND slow (round-1 lesson)
    __syncthreads();                     // all 256 producer entries confirmed
    for (int bb = k3; bb < 16; bb += 3) {
      const int tM = ((bb << 2) + p) << 7;   // batch bb, t in [p*128,(p+1)*128)
      const int mo = tM + ((w & 1) << 6);
      f32x4 acc[4][4] = {};
      const short* Ap = hs + (long)(mo + lr) * H_ + lk8;
      const short* Bp = pwb + (long)(no + lr) * H_ + lk8;
      for (int k0 = 0; k0 < H_; k0 += 32) {
        short8 af[4], bfr[4];
#pragma unroll
        for (int i = 0; i < 4; ++i) af[i] = *(const short8*)(Ap + (long)16 * i * H_ + k0);
#pragma unroll
        for (int j = 0; j < 4; ++j) bfr[j] = *(const short8*)(Bp + (long)16 * j * H_ + k0);
#pragma unroll
        for (int i = 0; i < 4; ++i)
#pragma unroll
          for (int j = 0; j < 4; ++j)
            acc[i][j] = mfma16(af[i], bfr[j], acc[i][j]);
      }
#pragma unroll
      for (int i = 0; i < 4; ++i) {
#pragma unroll
        for (int r = 0; r < 4; ++r) {
          int row = mo + 16 * i + 4 * q + r;
          int ysr = ys[row];
          float sum = 0.f;
#pragma unroll
          for (int j = 0; j < 4; ++j) {
            float v = acc[i][j][r] + pbv[j];
            sum += __expf(v);
            int col = no + 16 * j + lr;
            if (col == ysr) logit_y[row] = v;
          }
          sum += __shfl_xor(sum, 1); sum += __shfl_xor(sum, 2);
          sum += __shfl_xor(sum, 4); sum += __shfl_xor(sum, 8);
          if (lr == 0) sump_slot[row] = sum;   // plain store, unique producer
        }
      }
    }
  }
}

__global__ __launch_bounds__(256, 1) void scan_logits(
    const short* __restrict__ zxb, const short* __restrict__ mxb,
    const short* __restrict__ wmhT, const short* __restrict__ whT,
    short* __restrict__ hs,
    ull* __restrict__ h_ex,         // bf16[16][1024] as ull[2048], memset 0
    ull* __restrict__ m_ex,         // bf16[16][1024] as ull[2048], no init
    unsigned* __restrict__ flags_m, // [64] stride 16 dwords
    unsigned* __restrict__ flags_h, // [64*4] per-(WG,wave), stride 16 dwords
    unsigned* __restrict__ prog,    // [256] dense per-(WG,wave) progress
    const short* __restrict__ pwb,  // pred_w bf16 [V][H]
    const float* __restrict__ pb,   // pred_b
    const int* __restrict__ ys,
    float* __restrict__ sumexp_p,   // [128][BT_] per-(vb,half) partial expsums
    float* __restrict__ logit_y) {
  const int blk = blockIdx.x;
  const int tid = threadIdx.x;
  const int w = tid >> 6, lane = tid & 63;
  const int lr = lane & 15, q = lane >> 4;

  __shared__ float red1[4][16][16];          //  4 KB
  __shared__ float red2[4][4][16][16];       // 16 KB

  if (blk < NWG_) {
    // ================= SCAN (round-2 structure, unchanged protocol) ========
    const int g = blk;
    const int colg = g << 4;
    const int b = tid >> 4, cl = tid & 15;

    // ---- preload weights into registers (atomic loads: cannot rematerialize) ----
    short8 wmh_f[8];
#pragma unroll
    for (int kk = 0; kk < 8; ++kk) {
      const ull* p = (const ull*)(wmhT + (long)(colg + lr) * H_ + (w << 8) + (kk << 5) + (q << 3));
      ull lo = __hip_atomic_load(p, __ATOMIC_RELAXED, __HIP_MEMORY_SCOPE_WORKGROUP);
      ull hi = __hip_atomic_load(p + 1, __ATOMIC_RELAXED, __HIP_MEMORY_SCOPE_WORKGROUP);
      wmh_f[kk] = mk8(lo, hi);
    }
    short8 wh_f[4][8];
#pragma unroll
    for (int gt = 0; gt < 4; ++gt)
#pragma unroll
      for (int kk = 0; kk < 8; ++kk) {
        const ull* p = (const ull*)(whT + (long)(gt * H_ + colg + lr) * H_ + (w << 8) + (kk << 5) + (q << 3));
        ull lo = __hip_atomic_load(p, __ATOMIC_RELAXED, __HIP_MEMORY_SCOPE_WORKGROUP);
        ull hi = __hip_atomic_load(p + 1, __ATOMIC_RELAXED, __HIP_MEMORY_SCOPE_WORKGROUP);
        wh_f[gt][kk] = mk8(lo, hi);
      }

    float c = 0.f;
    const ull* hp = h_ex + lr * 256 + (w << 6) + (q << 1);
    const ull* mp = m_ex + lr * 256 + (w << 6) + (q << 1);
    const unsigned* fhp = flags_h + (((w << 4) + (lane >> 2)) * 4 + (lane & 3)) * 16;
    const unsigned* fmp = flags_m + ((w << 4) + lr) * 16;
    const int b2 = tid >> 2, ch = tid & 3;   // wave-0 funnel geometry
    ull* m_st = m_ex + (b2 << 8) + (colg >> 2) + ch;
    unsigned* h_st = (unsigned*)h_ex + (((b << 10) + colg + cl) >> 1);

    for (int t = 0; t < T_; ++t) {
      long rrow = (long)(b * T_ + t);
      const short* zrow = zxb + rrow * H4_ + colg + cl;
      short z0p = zrow[0 * H_], z1p = zrow[1 * H_], z2p = zrow[2 * H_], z3p = zrow[3 * H_];
      ull mxq = 0;
      if (w == 0)
        mxq = *(const ull*)(mxb + (long)(b2 * T_ + t) * H_ + colg + (ch << 2));

      // ---- phase 1: per-wave wait for h(t), m = mx_t * (h @ wmh) ----
      while (__hip_atomic_load(fhp, __ATOMIC_RELAXED, __HIP_MEMORY_SCOPE_AGENT)
             < (unsigned)t) {}

      ull lh[16];
#pragma unroll
      for (int kk = 0; kk < 8; ++kk) {
        lh[2 * kk]     = __hip_atomic_load(hp + (kk << 3),     __ATOMIC_RELAXED, __HIP_MEMORY_SCOPE_AGENT);
        lh[2 * kk + 1] = __hip_atomic_load(hp + (kk << 3) + 1, __ATOMIC_RELAXED, __HIP_MEMORY_SCOPE_AGENT);
      }
      f32x4 a1 = {};
#pragma unroll
      for (int kk = 0; kk < 8; ++kk)
        a1 = mfma16(mk8(lh[2 * kk], lh[2 * kk + 1]), wmh_f[kk], a1);
#pragma unroll
      for (int r = 0; r < 4; ++r) red1[w][q * 4 + r][lr] = a1[r];
      __syncthreads();                                   // sync#1

      if (w == 0) {   // wave0: reduce out of red1, publish m, drain, flag
        union { short4v s; ull u; } pk;
        union { short4v s; ull u; } mxu; mxu.u = mxq;
#pragma unroll
        for (int u = 0; u < 4; ++u) {
          float s = red1[0][b2][(ch << 2) + u] + red1[1][b2][(ch << 2) + u] +
                    red1[2][b2][(ch << 2) + u] + red1[3][b2][(ch << 2) + u];
          pk.s[u] = f2bf(bf2f(mxu.s[u]) * s);
        }
        __hip_atomic_store(m_st, pk.u, __ATOMIC_RELAXED, __HIP_MEMORY_SCOPE_AGENT);
        __builtin_amdgcn_s_waitcnt(0);   // wave0 stores committed
        if (tid == 0)
          __hip_atomic_store(&flags_m[g << 4], (unsigned)(t + 1),
                             __ATOMIC_RELAXED, __HIP_MEMORY_SCOPE_AGENT);
      }

      // ---- phase 2: per-wave wait for m(t), z = zx + m @ wh, gates ----
      while (__hip_atomic_load(fmp, __ATOMIC_RELAXED, __HIP_MEMORY_SCOPE_AGENT)
             < (unsigned)(t + 1)) {}

      ull lm[16];
#pragma unroll
      for (int kk = 0; kk < 8; ++kk) {
        lm[2 * kk]     = __hip_atomic_load(mp + (kk << 3),     __ATOMIC_RELAXED, __HIP_MEMORY_SCOPE_AGENT);
        lm[2 * kk + 1] = __hip_atomic_load(mp + (kk << 3) + 1, __ATOMIC_RELAXED, __HIP_MEMORY_SCOPE_AGENT);
      }
      f32x4 a2[4] = {};
#pragma unroll
      for (int kk = 0; kk < 8; ++kk) {
        short8 mf = mk8(lm[2 * kk], lm[2 * kk + 1]);
#pragma unroll
        for (int gt = 0; gt < 4; ++gt)
          a2[gt] = mfma16(mf, wh_f[gt][kk], a2[gt]);
      }
#pragma unroll
      for (int gt = 0; gt < 4; ++gt)
#pragma unroll
        for (int r = 0; r < 4; ++r)
          red2[w][gt][q * 4 + r][lr] = a2[gt][r];
      __syncthreads();                                   // sync#2

      {
        float zi = red2[0][0][b][cl] + red2[1][0][b][cl] + red2[2][0][b][cl] + red2[3][0][b][cl] + bf2f(z0p);
        float zf = red2[0][1][b][cl] + red2[1][1][b][cl] + red2[2][1][b][cl] + red2[3][1][b][cl] + bf2f(z1p);
        float zo = red2[0][2][b][cl] + red2[1][2][b][cl] + red2[2][2][b][cl] + red2[3][2][b][cl] + bf2f(z2p);
        float zu = red2[0][3][b][cl] + red2[1][3][b][cl] + red2[2][3][b][cl] + red2[3][3][b][cl] + bf2f(z3p);
        float ig = sigm(zi), fg = sigm(zf), og = sigm(zo), ug = tanh_f(zu);
        c = fg * c + ig * ug;
        float h = og * tanh_f(c);
        short hb = f2bf(h);
        unsigned hv = (unsigned)(unsigned short)hb;
        unsigned ov = (unsigned)__shfl_xor((int)hv, 1);
        unsigned packed = hv | (ov << 16);
        if ((lane & 1) == 0) {
          __hip_atomic_store(h_st, packed, __ATOMIC_RELAXED, __HIP_MEMORY_SCOPE_AGENT);
          // hs agent-scope: fresh at LIC before prog flag, so the workers'
          // plain cached loads (first touch after gate) are fresh.
          __hip_atomic_store((unsigned*)hs + (((rrow << 10) + colg + cl) >> 1),
                             packed, __ATOMIC_RELAXED, __HIP_MEMORY_SCOPE_AGENT);
        }
        __builtin_amdgcn_s_waitcnt(0);   // h + hs slices committed
        if (lane == 0) {
          __hip_atomic_store(&flags_h[((g << 2) + w) << 4], (unsigned)(t + 1),
                             __ATOMIC_RELAXED, __HIP_MEMORY_SCOPE_AGENT);
          __hip_atomic_store(&prog[(g << 2) + w], (unsigned)(t + 1),
                             __ATOMIC_RELAXED, __HIP_MEMORY_SCOPE_AGENT);
        }
      }
    }
  } else {
    // ================= LOGITS WORKERS (static vb partition) ===============
    const int wid = blk - NWG_;                 // 0..191
    const int vb  = ((wid & 7) << 3) | ((wid >> 3) & 7);  // XCD-affine slice
    const int k3  = wid >> 6;                   // 0..2: bb-split of three
    logits_work_static(tid, vb, k3, hs, pwb, pb, ys, sumexp_p, logit_y, prog);
  }
}

// ---------------------------------------------------------------------------
// Fold the 128 per-(vb,half) expsum partials per row; per-row NLL.
__global__ __launch_bounds__(256) void row_nll(const float* __restrict__ sumexp_p,
                                               const float* __restrict__ ly,
                                               float* __restrict__ nll) {
  int r = blockIdx.x * 256 + threadIdx.x;   // grid 32 -> 8192 rows
  float s = 0.f;
  for (int vb2 = 0; vb2 < 128; ++vb2) s += sumexp_p[((long)vb2 << 13) + r];
  nll[r] = logf(s) - ly[r];
}

__global__ __launch_bounds__(256) void reduce_nll(const float* __restrict__ nll,
                                                  float* __restrict__ out) {
  __shared__ float buf[256];
  float s = 0.f;
  for (int r = threadIdx.x; r < BT_; r += 256)
    s += nll[r];
  buf[threadIdx.x] = s;
  __syncthreads();
  for (int off = 128; off > 0; off >>= 1) {
    if (threadIdx.x < off) buf[threadIdx.x] += buf[threadIdx.x + off];
    __syncthreads();
  }
  if (threadIdx.x == 0) out[0] = buf[0] * (1.0f / BT_);
}

// ---------------------------------------------------------------------------
extern "C" void kernel_launch(void* const* d_in, const int* in_sizes, int n_in,
                              void* d_out, int out_size, void* d_ws, size_t ws_size,
                              hipStream_t stream) {
  const int*   xs     = (const int*)d_in[0];
  const int*   ys     = (const int*)d_in[1];
  const float* embw   = (const float*)d_in[2];
  const float* wx     = (const float*)d_in[3];
  const float* wh     = (const float*)d_in[4];
  const float* wmx    = (const float*)d_in[5];
  const float* wmh    = (const float*)d_in[6];
  const float* bias   = (const float*)d_in[7];
  const float* gx     = (const float*)d_in[8];
  const float* gh     = (const float*)d_in[9];
  const float* gmx    = (const float*)d_in[10];
  const float* gmh    = (const float*)d_in[11];
  const float* pred_w = (const float*)d_in[12];
  const float* pred_b = (const float*)d_in[13];
  float* out = (float*)d_out;

  char* base = (char*)d_ws;
  size_t off = 0;
  auto alloc = [&](size_t bytes) -> void* {
    void* p = base + off;
    off = (off + bytes + 255) & ~(size_t)255;
    return p;
  };
  short* xb     = (short*)alloc((size_t)BT_ * E_ * 2);   //  8 MB
  short* zxb    = (short*)alloc((size_t)BT_ * H4_ * 2);  // 64 MB
  short* mxb    = (short*)alloc((size_t)BT_ * H_ * 2);   // 16 MB
  short* hs     = (short*)alloc((size_t)BT_ * H_ * 2);   // 16 MB
  short* wxT    = (short*)alloc((size_t)H4_ * E_ * 2);   //  4 MB
  short* whT    = (short*)alloc((size_t)H4_ * H_ * 2);   //  8 MB
  short* wmxT   = (short*)alloc((size_t)H_ * E_ * 2);    //  1 MB
  short* wmhT   = (short*)alloc((size_t)H_ * H_ * 2);    //  2 MB
  short* pwb    = (short*)alloc((size_t)V_ * H_ * 2);    // 16 MB
  float* scx    = (float*)alloc(H4_ * 4);
  float* sch    = (float*)alloc(H4_ * 4);
  float* scmx   = (float*)alloc(H_ * 4);
  float* scmh   = (float*)alloc(H_ * 4);
  float* l_y    = (float*)alloc(BT_ * 4);
  float* sump   = (float*)alloc((size_t)128 * BT_ * 4);  //  4 MB per-(vb,half) partials
  float* nll    = (float*)alloc(BT_ * 4);                // 32 KB
  ull*   m_ex   = (ull*)alloc((size_t)B_ * H_ * 2);      // 32 KB, no init needed
  // ---- zero zone (one memset covers all of these) ----
  size_t z0 = off;
  unsigned* flags_m = (unsigned*)alloc(NWG_ * 16 * 4);       //  4 KB
  unsigned* flags_h = (unsigned*)alloc(NWG_ * 4 * 16 * 4);   // 16 KB
  unsigned* prog    = (unsigned*)alloc(NWG_ * 4 * 4);        //  1 KB dense
  ull*      h_ex    = (ull*)alloc((size_t)B_ * H_ * 2);      // 32 KB
  size_t zlen = off - z0;

  hipMemsetAsync(base + z0, 0, zlen, stream);

  // weight norm -> transposed bf16 copies
  colscale<<<H4_ / 256, 256, 0, stream>>>(wx, gx, scx, E_, H4_);
  colscale<<<H4_ / 256, 256, 0, stream>>>(wh, gh, sch, H_, H4_);
  colscale<<<H_ / 256, 256, 0, stream>>>(wmx, gmx, scmx, E_, H_);
  colscale<<<H_ / 256, 256, 0, stream>>>(wmh, gmh, scmh, H_, H_);
  transpose_cast<<<(E_ / 32) * (H4_ / 32), 256, 0, stream>>>(wx, scx, wxT, E_, H4_);
  transpose_cast<<<(H_ / 32) * (H4_ / 32), 256, 0, stream>>>(wh, sch, whT, H_, H4_);
  transpose_cast<<<(E_ / 32) * (H_ / 32), 256, 0, stream>>>(wmx, scmx, wmxT, E_, H_);
  transpose_cast<<<(H_ / 32) * (H_ / 32), 256, 0, stream>>>(wmh, scmh, wmhT, H_, H_);
  castbf<<<((long)V_ * H_) / 1024, 256, 0, stream>>>(pred_w, pwb, (long)V_ * H_);

  // embed + input-dependent projections
  embed_gather<<<BT_, 256, 0, stream>>>(xs, embw, xb);
  gemm_bt<<<(BT_ / 128) * (H4_ / 128), 256, 0, stream>>>(xb, wxT, bias, zxb, BT_, H4_, E_);
  gemm_bt<<<(BT_ / 128) * (H_ / 128), 256, 0, stream>>>(xb, wmxT, nullptr, mxb, BT_, H_, E_);

  // fused: sequential mLSTM scan (64 WGs) + in-flight logits GEMM
  // (192 static-vb workers, staggered phase release, atomic-free partials)
  scan_logits<<<NWG_ + NLOG_, 256, 0, stream>>>(zxb, mxb, wmhT, whT, hs,
                                                h_ex, m_ex, flags_m, flags_h, prog,
                                                pwb, pred_b, ys, sump, l_y);

  row_nll<<<BT_ / 256, 256, 0, stream>>>(sump, l_y, nll);
  reduce_nll<<<1, 256, 0, stream>>>(nll, out);
}